// Round 1
// 2971.977 us; speedup vs baseline: 1.1638x; 1.1638x over previous
//
#include <hip/hip_runtime.h>
#include <stdint.h>

// ---------------------------------------------------------------------------
// LSTM_14242111554073  (B=32, S=512, IN=512, H=1024, fp32 in/out)
// Phase 1: gx = x @ [wxf|wxi|wxo|wxc]  (bf16 MFMA GEMM, 16384x512x4096)
// Phase 2: persistent scan, 128 WGs (1/CU). Wh slice in LDS.
//   R1 change: FLAG-FREE cross-WG sync. hhist is pre-filled with 0xFF
//   (bf16 -NaN sentinel, unreachable since |h|<1). Producers store h rows as
//   single sc1 dwordx4 (write-through LLC). Consumers load A-fragments with
//   sc0+sc1 bypass loads and retry per 32-k chunk while any dword is still
//   0xFFFFFFFF; MFMAs for a chunk fire as soon as it lands. This merges
//   {store-drain, atomicAdd, flag-poll, data-load} (~4 LLC transits) into 1,
//   and removes 2 of 4 per-step barriers.
// ---------------------------------------------------------------------------

typedef short bf16x8 __attribute__((ext_vector_type(8)));
typedef float f32x4  __attribute__((ext_vector_type(4)));
typedef unsigned int uint4v __attribute__((ext_vector_type(4)));

#define MFMA16(a, b, c) __builtin_amdgcn_mfma_f32_16x16x32_bf16((a), (b), (c), 0, 0, 0)

__device__ __forceinline__ unsigned short f2bf(float f) {
    unsigned int u = __builtin_bit_cast(unsigned int, f);
    u = (u + 0x7FFFu + ((u >> 16) & 1u)) >> 16;   // RNE
    return (unsigned short)u;
}
__device__ __forceinline__ float bf2f(unsigned short h) {
    unsigned int u = ((unsigned int)h) << 16;
    return __builtin_bit_cast(float, u);
}
__device__ __forceinline__ float sigmoidf_(float x) { return 1.0f / (1.0f + __expf(-x)); }
__device__ __forceinline__ float tanhf_(float x)    { return 1.0f - 2.0f / (__expf(2.0f * x) + 1.0f); }

// ---------------------------------------------------------------------------
// Kernel 1: gx GEMM.  C[16384 x 4096] = X[16384 x 512] @ Wx[512 x 4096], bf16 out.
// (unchanged this round — scan dominates)
// ---------------------------------------------------------------------------
__global__ void __launch_bounds__(256) gx_gemm(
    const float* __restrict__ X,
    const float* __restrict__ Wf, const float* __restrict__ Wi,
    const float* __restrict__ Wo, const float* __restrict__ Wc,
    unsigned short* __restrict__ gxOut)
{
    __shared__ unsigned short As[128 * 40];
    __shared__ unsigned short Bs[128 * 40];

    const int tid  = threadIdx.x;
    const int lane = tid & 63;
    const int wid  = tid >> 6;
    const int lr   = lane & 15;
    const int lq   = lane >> 4;

    const int m0 = blockIdx.x * 128;
    const int n0 = blockIdx.y * 128;
    const float* Wg = (n0 < 1024) ? Wf : (n0 < 2048) ? Wi : (n0 < 3072) ? Wo : Wc;
    const int ncol0 = n0 & 1023;

    const int mw = (wid & 1) * 64;
    const int nw = (wid >> 1) * 64;

    f32x4 acc[4][4];
#pragma unroll
    for (int i = 0; i < 4; i++)
#pragma unroll
        for (int j = 0; j < 4; j++) acc[i][j] = (f32x4){0.f, 0.f, 0.f, 0.f};

    for (int k0 = 0; k0 < 512; k0 += 32) {
#pragma unroll
        for (int i = 0; i < 4; i++) {
            int s   = tid + i * 256;
            int row = s >> 3;
            int c4  = s & 7;
            float4 v = *(const float4*)(X + (size_t)(m0 + row) * 512 + k0 + c4 * 4);
            ushort4 h;
            h.x = f2bf(v.x); h.y = f2bf(v.y); h.z = f2bf(v.z); h.w = f2bf(v.w);
            *(ushort4*)(As + row * 40 + c4 * 4) = h;
        }
#pragma unroll
        for (int i = 0; i < 4; i++) {
            int s  = tid + i * 256;
            int kk = s >> 5;
            int c4 = s & 31;
            float4 v = *(const float4*)(Wg + (size_t)(k0 + kk) * 1024 + ncol0 + c4 * 4);
            Bs[(c4 * 4 + 0) * 40 + kk] = f2bf(v.x);
            Bs[(c4 * 4 + 1) * 40 + kk] = f2bf(v.y);
            Bs[(c4 * 4 + 2) * 40 + kk] = f2bf(v.z);
            Bs[(c4 * 4 + 3) * 40 + kk] = f2bf(v.w);
        }
        __syncthreads();

        bf16x8 af[4], bfr[4];
#pragma unroll
        for (int tm = 0; tm < 4; tm++)
            af[tm] = *(const bf16x8*)(As + (mw + tm * 16 + lr) * 40 + lq * 8);
#pragma unroll
        for (int tn = 0; tn < 4; tn++)
            bfr[tn] = *(const bf16x8*)(Bs + (nw + tn * 16 + lr) * 40 + lq * 8);
#pragma unroll
        for (int tm = 0; tm < 4; tm++)
#pragma unroll
            for (int tn = 0; tn < 4; tn++)
                acc[tm][tn] = MFMA16(af[tm], bfr[tn], acc[tm][tn]);
        __syncthreads();
    }

#pragma unroll
    for (int tm = 0; tm < 4; tm++)
#pragma unroll
        for (int tn = 0; tn < 4; tn++)
#pragma unroll
            for (int r = 0; r < 4; r++) {
                int row = m0 + mw + tm * 16 + lq * 4 + r;
                int col = n0 + nw + tn * 16 + lr;
                gxOut[(size_t)row * 4096 + col] = f2bf(acc[tm][tn][r]);
            }
}

// ---------------------------------------------------------------------------
// Kernel 2: persistent scan. 128 WGs x 256 threads. WG w owns h-cols
// j0=w*8..j0+7 (32 gate cols). LDS (dynamic):
//   Wlds  [32 cols][1032 k] bf16 (col stride 1032 ush = 2064 B) : 66048 B
//   glds  [4 waves][32 b][34 col] f32 partials                  : 17408 B
//   blds  [32] f32                                              :   128 B
// total 83584 B -> 1 WG/CU (co-residency: 128 WGs on 256 CUs guaranteed)
// ---------------------------------------------------------------------------
#define NWG 128
#define LDS2_BYTES 83584

__global__ void __launch_bounds__(256, 1) lstm_scan(
    const float* __restrict__ Whf, const float* __restrict__ Whi,
    const float* __restrict__ Who, const float* __restrict__ Whc,
    const float* __restrict__ Bf,  const float* __restrict__ Bi,
    const float* __restrict__ Bo,  const float* __restrict__ Bc,
    const unsigned short* __restrict__ gx,
    unsigned short* __restrict__ hhist,   // [512][32][1024] bf16, slot t = h_t
                                          // pre-filled 0xFF (sentinel)
    float* __restrict__ out)
{
    extern __shared__ char lds[];
    unsigned short* Wlds = (unsigned short*)lds;            // 66048 B
    float* glds = (float*)(lds + 66048);                    // 17408 B: [4][32][34]
    float* blds = (float*)(lds + 83456);                    // 128 B

    const int tid  = threadIdx.x;
    const int w    = blockIdx.x;
    const int j0   = w * 8;
    const int lane = tid & 63;
    const int kq   = tid >> 6;          // wave id == K-split chunk
    const int lr   = lane & 15;
    const int lq   = lane >> 4;

    // ---- biases ----
    if (tid < 32) {
        int g = tid >> 3, jj = tid & 7;
        const float* bp = (g == 0) ? Bf : (g == 1) ? Bi : (g == 2) ? Bo : Bc;
        blds[tid] = bp[j0 + jj];
    }
    // ---- Wh slice -> LDS bf16 col-major [col][k] ----
#pragma unroll 4
    for (int i = 0; i < 128; i++) {
        int e = i * 256 + tid;          // 0..32767
        int k = e >> 5;
        int c = e & 31;
        int g = c >> 3, jj = c & 7;
        const float* wp = (g == 0) ? Whf : (g == 1) ? Whi : (g == 2) ? Who : Whc;
        Wlds[c * 1032 + k] = f2bf(wp[(size_t)k * 1024 + j0 + jj]);
    }

    const int cb = tid >> 3;            // epilogue batch row
    const int cj = tid & 7;             // epilogue h-col within slice
    float c_reg = 0.f;

    __syncthreads();

    for (int t = 0; t < 512; t++) {
        // ---- prefetch gx for this step (overlaps the sentinel sweep) ----
        const unsigned short* gxr = gx + ((size_t)(cb * 512 + t)) * 4096 + j0 + cj;
        float gxv[4];
#pragma unroll
        for (int g = 0; g < 4; g++) gxv[g] = bf2f(gxr[(size_t)g * 1024]);

        if (t > 0) {
            // ---- sentinel-sweep GEMM: load h_t fragments via sc0+sc1 bypass,
            //      retry per 32-k chunk, fire MFMAs as chunks become ready ----
            const unsigned short* hsrc  = hhist + (size_t)t * 32768;
            const unsigned short* bbase = Wlds + kq * 256 + lq * 8;

            f32x4 acc[2][2];
#pragma unroll
            for (int a = 0; a < 2; a++)
#pragma unroll
                for (int b = 0; b < 2; b++) acc[a][b] = (f32x4){0.f, 0.f, 0.f, 0.f};

            uint4v f0[8], f1[8];
            unsigned int pend = 0xFFu;
            while (pend) {
#pragma unroll
                for (int ks = 0; ks < 8; ks++) {
                    if (pend & (1u << ks)) {
                        int kk = (ks + w) & 7;   // stagger sweep order per WG
                        const unsigned short* p0 = hsrc + (lr) * 1024
                                                   + kq * 256 + kk * 32 + lq * 8;
                        const unsigned short* p1 = hsrc + (16 + lr) * 1024
                                                   + kq * 256 + kk * 32 + lq * 8;
                        asm volatile("global_load_dwordx4 %0, %1, off sc0 sc1"
                                     : "=v"(f0[ks]) : "v"(p0));
                        asm volatile("global_load_dwordx4 %0, %1, off sc0 sc1"
                                     : "=v"(f1[ks]) : "v"(p1));
                    }
                }
                asm volatile("s_waitcnt vmcnt(0)" ::: "memory");
                __builtin_amdgcn_sched_barrier(0);

                unsigned int np = 0;
#pragma unroll
                for (int ks = 0; ks < 8; ks++) {
                    if (pend & (1u << ks)) {
                        int kk = (ks + w) & 7;
                        uint4v u0 = f0[ks], u1 = f1[ks];
                        bool dirty = (u0[0] == 0xFFFFFFFFu) | (u0[1] == 0xFFFFFFFFu)
                                   | (u0[2] == 0xFFFFFFFFu) | (u0[3] == 0xFFFFFFFFu)
                                   | (u1[0] == 0xFFFFFFFFu) | (u1[1] == 0xFFFFFFFFu)
                                   | (u1[2] == 0xFFFFFFFFu) | (u1[3] == 0xFFFFFFFFu);
                        if (__any(dirty)) {
                            np |= 1u << ks;
                        } else {
                            bf16x8 a0 = __builtin_bit_cast(bf16x8, f0[ks]);
                            bf16x8 a1 = __builtin_bit_cast(bf16x8, f1[ks]);
                            bf16x8 b0 = *(const bf16x8*)(bbase + (lr) * 1032 + kk * 32);
                            bf16x8 b1 = *(const bf16x8*)(bbase + (16 + lr) * 1032 + kk * 32);
                            acc[0][0] = MFMA16(a0, b0, acc[0][0]);
                            acc[0][1] = MFMA16(a0, b1, acc[0][1]);
                            acc[1][0] = MFMA16(a1, b0, acc[1][0]);
                            acc[1][1] = MFMA16(a1, b1, acc[1][1]);
                        }
                    }
                }
                pend = np;
            }

            // partials: [kq][row=batch][col=gate]  (C/D: row=lq*4+r, col=lr)
#pragma unroll
            for (int tm = 0; tm < 2; tm++)
#pragma unroll
                for (int tn = 0; tn < 2; tn++)
#pragma unroll
                    for (int r = 0; r < 4; r++)
                        glds[kq * 1088 + (tm * 16 + lq * 4 + r) * 34 + tn * 16 + lr]
                            = acc[tm][tn][r];
        }
        __syncthreads();   // barrier B: partials visible

        // ---- pointwise epilogue: thread (cb, cj) ----
        float sg[4];
#pragma unroll
        for (int g = 0; g < 4; g++) {
            float dot = 0.f;
            if (t > 0) {
#pragma unroll
                for (int p = 0; p < 4; p++)
                    dot += glds[p * 1088 + cb * 34 + g * 8 + cj];
            }
            sg[g] = sigmoidf_(dot + gxv[g] + blds[g * 8 + cj]);
        }
        float cn = sg[0] * c_reg + sg[1] * sg[3];   // f*c + i*sigmoid(cand)
        c_reg = cn;
        float hn = sg[2] * tanhf_(cn);

        if (t < 511) {
            // ---- h_{t+1}: gather 8 cols of row cb into one sc1 dwordx4 ----
            unsigned int hb = (unsigned int)f2bf(hn);
            unsigned int nb = (unsigned int)__shfl_xor((int)hb, 1);
            unsigned int v  = (hb & 0xFFFFu) | (nb << 16);     // cols (cj, cj+1), even cj
            unsigned int v2 = (unsigned int)__shfl_xor((int)v, 2);
            unsigned int v4 = (unsigned int)__shfl_xor((int)v, 4);
            unsigned int v6 = (unsigned int)__shfl_xor((int)v2, 4);
            if (cj == 0) {
                uint4v q;
                q[0] = v; q[1] = v2; q[2] = v4; q[3] = v6;     // cols 0..7
                unsigned short* dst = hhist + (size_t)(t + 1) * 32768
                                      + cb * 1024 + j0;
                asm volatile("global_store_dwordx4 %0, %1, off sc1"
                             :: "v"(dst), "v"(q) : "memory");
            }
            out[((size_t)cb * 512 + t) * 1024 + j0 + cj] = sg[2];   // seq out = o gate
        } else {
            out[((size_t)cb * 512 + t) * 1024 + j0 + cj] = sg[2];
            out[16777216 + cb * 1024 + j0 + cj]          = hn;   // ht
            out[16777216 + 32768 + cb * 1024 + j0 + cj]  = cn;   // ct
        }
        __syncthreads();   // barrier D: glds consumed before next step's GEMM
    }
}

__global__ void ws_diag(float* out, float mb) { out[threadIdx.x] = -mb; }

extern "C" void kernel_launch(void* const* d_in, const int* in_sizes, int n_in,
                              void* d_out, int out_size, void* d_ws, size_t ws_size,
                              hipStream_t stream)
{
    const float* x   = (const float*)d_in[0];
    const float* wxf = (const float*)d_in[1];
    const float* whf = (const float*)d_in[2];
    const float* bhf = (const float*)d_in[3];
    const float* wxi = (const float*)d_in[4];
    const float* whi = (const float*)d_in[5];
    const float* bhi = (const float*)d_in[6];
    const float* wxo = (const float*)d_in[7];
    const float* who = (const float*)d_in[8];
    const float* bho = (const float*)d_in[9];
    const float* wxc = (const float*)d_in[10];
    const float* whc = (const float*)d_in[11];
    const float* bhc = (const float*)d_in[12];
    float* out = (float*)d_out;

    const size_t GX_BYTES = (size_t)16384 * 4096 * 2;    // 134217728
    const size_t HH_BYTES = (size_t)512 * 32 * 1024 * 2; //  33554432
    const size_t NEED = GX_BYTES + HH_BYTES;

    if (ws_size < NEED) {
        ws_diag<<<dim3(1), dim3(256), 0, stream>>>(out, (float)(ws_size >> 20));
        return;
    }

    unsigned short* gxbuf = (unsigned short*)d_ws;
    unsigned short* hh    = (unsigned short*)((char*)d_ws + GX_BYTES);

    (void)hipFuncSetAttribute((const void*)lstm_scan,
                              hipFuncAttributeMaxDynamicSharedMemorySize, LDS2_BYTES);

    gx_gemm<<<dim3(128, 32), dim3(256), 0, stream>>>(x, wxf, wxi, wxo, wxc, gxbuf);
    // sentinel-fill hhist: bf16 0xFFFF (-NaN) is unreachable for real h (|h|<1)
    hipMemsetAsync(hh, 0xFF, HH_BYTES, stream);
    lstm_scan<<<dim3(NWG), dim3(256), LDS2_BYTES, stream>>>(
        whf, whi, who, whc, bhf, bhi, bho, bhc, gxbuf, hh, out);
}